// Round 9
// baseline (100.534 us; speedup 1.0000x reference)
//
#include <hip/hip_runtime.h>
#include <math.h>

// Mamba selective scan:
//   u, delta, z : (2, 2048, 1024) f32 ; A : (2048, 16) f32
//   B, C : (2, 16, 1024) f32 ; D, delta_bias : (2048,) f32 ; softplus flag
// Output y : (2, 2048, 1024) f32
//
// v15: 4 waves/row (CL=8, 128 chunks), near-barrier-free:
//   - wave w owns chunks [32w..32w+31] = contiguous 256-elem row slice ->
//     phase0 / LDS region / pass2-writeback / epilogue all wave-private;
//     exactly ONE __syncthreads (cross-wave totals exchange).
//   - DPP segmented scan with FIXED row_bcast masking (r8 bug: bcast:15
//     leaks lane31 -> lanes 32-47; row_mask=0xA makes rows 0,2 identity).
//   - rank-1 decay: scan scalar ss; cross-wave compose of (ss_w, x_w).
//   - interleaved workspace W[b][i][cg][8] = {B0,B1,C0,C1,B2,B3,C2,C3}:
//     pass2 reads 4 ADJACENT float4 (64B/thread, 8KB/wave contiguous).
//   - depth-2 prefetch rings, no reg cap (r2/r4), target VGPR <= 64.
constexpr int Bsz = 2, Dm = 2048, L = 1024, N = 16;
constexpr int CL = 8;           // steps per chunk
constexpr int WPR = 4;          // waves per row (32 chunks each)
constexpr int TPB = WPR * 64;   // 256 threads, one row per block
constexpr int ISTR2 = 33;       // float2 stride per step within wave region
constexpr int LROW2 = CL * ISTR2;   // 264 float2 per wave region
constexpr float LOG2E = 1.4426950408889634f;
constexpr float RLOG2E = 0.6931471805599453f;   // ln 2

#define EXP2(x) __builtin_amdgcn_exp2f(x)

// DPP lane-shift on the VALU pipe; masked/invalid lanes receive old = 0
// (identity for the affine scan). ctrl: 0x111=row_shr:1 0x112=row_shr:2
// 0x114=row_shr:4 0x118=row_shr:8 0x142=row_bcast:15.
#define DPPF(CTRL, RM, v) __builtin_bit_cast(float, __builtin_amdgcn_update_dpp( \
        0, __builtin_bit_cast(int, (float)(v)), (CTRL), (RM), 0xF, false))

// One affine-scan stage over (ss, x[8]) with window-decay exp2(A2[n]*ss).
#define COMBINE_STAGE(CTRL, RM) do {                                      \
    const float ssp_ = DPPF(CTRL, RM, ss);                                \
    float xp_[8];                                                         \
    _Pragma("unroll") for (int n_ = 0; n_ < 8; ++n_)                      \
        xp_[n_] = DPPF(CTRL, RM, x[n_]);                                  \
    _Pragma("unroll") for (int n_ = 0; n_ < 8; ++n_)                      \
        x[n_] = fmaf(EXP2(A2[n_] * ss), xp_[n_], x[n_]);                  \
    ss += ssp_;                                                           \
} while (0)

// ---------------------------------------------------------------------------
// Transform B,C into interleaved scan layout (CL=8, 128 chunks):
//   W[b*8192 + i*1024 + cg*8 + g], g order {B0,B1,C0,C1,B2,B3,C2,C3}
//   (quad = (g&1) + 2*(g>>2), src = C if (g>>1)&1 else B), l = cg*8 + i.
// Scan thread (h,c) of wave w: base g = 4h at cg = w*32+c -> 4 adjacent
// float4 per step (B-pair then C-pair), 64 B contiguous.
// ---------------------------------------------------------------------------
__global__ __launch_bounds__(256) void transform_bc_kernel(
    const float* __restrict__ B_g, const float* __restrict__ C_g,
    float4* __restrict__ W4)
{
    const int o = threadIdx.x + 256 * blockIdx.x;   // 8192 float4 per b
    const int b = blockIdx.y;
    const int g = o & 7, cg = (o >> 3) & 127, i = o >> 10;
    const int quad = (g & 1) + 2 * (g >> 2);
    const float* __restrict__ src = ((g >> 1) & 1) ? C_g : B_g;
    const int l = cg * CL + i;
    float4 v;
    v.x = src[(size_t)(b * N + 4 * quad + 0) * L + l];
    v.y = src[(size_t)(b * N + 4 * quad + 1) * L + l];
    v.z = src[(size_t)(b * N + 4 * quad + 2) * L + l];
    v.w = src[(size_t)(b * N + 4 * quad + 3) * L + l];
    W4[(size_t)b * 8192 + o] = v;
}

// ---------------------------------------------------------------------------
// Scan kernel: 4 waves = 1 row. Wave w owns chunks cg = w*32 .. w*32+31.
// lane = h*32 + c: h = n-half (8 states), c = chunk-in-wave.
// ---------------------------------------------------------------------------
template<bool XF>
__global__ __launch_bounds__(TPB) void mamba_scan15_kernel(
    const float* __restrict__ u_g, const float* __restrict__ delta_g,
    const float* __restrict__ A_g,
    const float* __restrict__ B_g, const float* __restrict__ C_g,
    const float4* __restrict__ W4,
    const float* __restrict__ D_g, const float* __restrict__ z_g,
    const float* __restrict__ bias_g, const int* __restrict__ sp_g,
    float* __restrict__ y_g)
{
    __shared__ float2 du_s[WPR * LROW2];  // wave-private: (dtp,u); .x later y_core
    __shared__ float xw_s[WPR][16];       // per-wave inclusive totals
    __shared__ float ssw_s[WPR];          // per-wave dtp totals

    const int tid = threadIdx.x;
    const int w = tid >> 6;                    // wave id 0..3
    const int lane = tid & 63;
    const int h = lane >> 5;                   // n-half: states h*8 .. h*8+7
    const int c = lane & 31;                   // chunk-in-wave
    const int cg = w * 32 + c;                 // global chunk 0..127
    const int row = blockIdx.x;
    const int b = row >> 11;                   // row / Dm
    const int d = row & (Dm - 1);
    const int sp = sp_g[0];
    const float bias = bias_g[d];
    const int lb = w * LROW2;                  // wave-private LDS base

    // ---- Phase 0: wave-private coalesced load of own 256-elem slice ----
    {
        const int l0 = w * 256 + 4 * lane;     // my float4 within the row
        const size_t gb = (size_t)row * L + l0;
        const float4 d4 = *reinterpret_cast<const float4*>(&delta_g[gb]);
        const float4 u4 = *reinterpret_cast<const float4*>(&u_g[gb]);
        const float dv[4] = {d4.x, d4.y, d4.z, d4.w};
        const float uv[4] = {u4.x, u4.y, u4.z, u4.w};
#pragma unroll
        for (int k = 0; k < 4; ++k) {
            const int li = 4 * lane + k;       // local 0..255
            const float t = dv[k] + bias;
            // softplus: max(t,0) + ln(1 + 2^(-|t|*log2e))
            const float e = EXP2(-fabsf(t) * LOG2E);
            const float p_ = sp ? (fmaxf(t, 0.f) +
                                   __builtin_amdgcn_logf(1.f + e) * RLOG2E)
                                : t;
            du_s[lb + (li & (CL - 1)) * ISTR2 + (li >> 3)] = make_float2(p_, uv[k]);
        }
    }
    // no barrier: wave-private (same-wave lgkmcnt orders LDS)

    float A2[8];
#pragma unroll
    for (int g = 0; g < 2; ++g) {
        const float4 a4 = *reinterpret_cast<const float4*>(&A_g[d * N + h * 8 + g * 4]);
        A2[g * 4 + 0] = a4.x * LOG2E; A2[g * 4 + 1] = a4.y * LOG2E;
        A2[g * 4 + 2] = a4.z * LOG2E; A2[g * 4 + 3] = a4.w * LOG2E;
    }
    const size_t base = (size_t)b * 8192 + cg * 8 + 4 * h;  // float4 units
    const float Dd = D_g[d];

    // ---- Pass 1: chunk-local zero-init scan (8 steps), depth-2 B ring ----
    float x[8];
#pragma unroll
    for (int n = 0; n < 8; ++n) x[n] = 0.f;
    float ss = 0.f;

    if (XF) {
        float4 rb0[2], rb1[2];
#pragma unroll
        for (int j = 0; j < 2; ++j) {
            rb0[j] = W4[base + j * 1024];
            rb1[j] = W4[base + j * 1024 + 1];
        }
#pragma unroll
        for (int i = 0; i < CL; ++i) {
            const float2 du = du_s[lb + i * ISTR2 + c];
            const float dtp = du.x;
            const float dtu = du.x * du.y;
            ss += dtp;
            const float4 B0 = rb0[i & 1];
            const float4 B1 = rb1[i & 1];
            if (i + 2 < CL) {
                rb0[i & 1] = W4[base + (i + 2) * 1024];
                rb1[i & 1] = W4[base + (i + 2) * 1024 + 1];
            }
            const float bv[8] = {B0.x, B0.y, B0.z, B0.w, B1.x, B1.y, B1.z, B1.w};
#pragma unroll
            for (int n = 0; n < 8; ++n) {
                const float a = EXP2(dtp * A2[n]);
                x[n] = fmaf(a, x[n], dtu * bv[n]);
            }
        }
    } else {
        const int k0 = 2 * h;
#pragma unroll 2
        for (int i = 0; i < CL; ++i) {
            const float2 du = du_s[lb + i * ISTR2 + c];
            const float dtp = du.x;
            const float dtu = du.x * du.y;
            ss += dtp;
            const int l = cg * CL + i;
            float4 B0, B1;
#pragma unroll
            for (int q = 0; q < 4; ++q) {
                (&B0.x)[q] = B_g[(size_t)(b * N + 4 * k0 + q) * L + l];
                (&B1.x)[q] = B_g[(size_t)(b * N + 4 * k0 + 4 + q) * L + l];
            }
            const float bv[8] = {B0.x, B0.y, B0.z, B0.w, B1.x, B1.y, B1.z, B1.w};
#pragma unroll
            for (int n = 0; n < 8; ++n) {
                const float a = EXP2(dtp * A2[n]);
                x[n] = fmaf(a, x[n], dtu * bv[n]);
            }
        }
    }

    // ---- Combine level 1: 32-lane segmented affine scan via DPP ----
    COMBINE_STAGE(0x111, 0xF);   // row_shr:1
    COMBINE_STAGE(0x112, 0xF);   // row_shr:2
    COMBINE_STAGE(0x114, 0xF);   // row_shr:4
    COMBINE_STAGE(0x118, 0xF);   // row_shr:8
    COMBINE_STAGE(0x142, 0xA);   // row_bcast:15 -> rows 1,3 ONLY (r8 bug fix)

    // ---- Publish wave totals; the ONE barrier ----
    if (c == 31) {
#pragma unroll
        for (int n = 0; n < 8; ++n) xw_s[w][h * 8 + n] = x[n];
        if (h == 0) ssw_s[w] = ss;
    }
    __syncthreads();

    // ---- Wave prefix compose (<=3 affine terms), then exclusive shift ----
    float X[8];
#pragma unroll
    for (int n = 0; n < 8; ++n) X[n] = 0.f;
    for (int v = 0; v < WPR - 1; ++v) {
        if (v < w) {
            const float sv = ssw_s[v];
#pragma unroll
            for (int n = 0; n < 8; ++n)
                X[n] = fmaf(EXP2(A2[n] * sv), X[n], xw_s[v][h * 8 + n]);
        }
    }
    {
        const float ss1 = DPPF(0x111, 0xF, ss);
        const float ssb = DPPF(0x142, 0xA, ss);
        const float sse = (c == 16) ? ssb : ss1;   // exclusive dtp-prefix
#pragma unroll
        for (int n = 0; n < 8; ++n) {
            const float x1 = DPPF(0x111, 0xF, x[n]);
            const float xb = DPPF(0x142, 0xA, x[n]);
            const float xe = (c == 16) ? xb : x1;  // exclusive within wave
            x[n] = fmaf(EXP2(A2[n] * sse), X[n], xe);   // + wave prefix
        }
    }

    // ---- Pass 2: rescan with init states (8 steps), depth-2 B+C ring ----
    if (XF) {
        float4 r0[2], r1[2], r2[2], r3[2];
#pragma unroll
        for (int j = 0; j < 2; ++j) {
            r0[j] = W4[base + j * 1024];
            r1[j] = W4[base + j * 1024 + 1];
            r2[j] = W4[base + j * 1024 + 2];
            r3[j] = W4[base + j * 1024 + 3];
        }
#pragma unroll
        for (int i = 0; i < CL; ++i) {
            const float2 du = du_s[lb + i * ISTR2 + c];
            const float dtp = du.x;
            const float uu = du.y;
            const float dtu = dtp * uu;
            const float4 B0 = r0[i & 1], B1 = r1[i & 1];
            const float4 C0 = r2[i & 1], C1 = r3[i & 1];
            if (i + 2 < CL) {
                r0[i & 1] = W4[base + (i + 2) * 1024];
                r1[i & 1] = W4[base + (i + 2) * 1024 + 1];
                r2[i & 1] = W4[base + (i + 2) * 1024 + 2];
                r3[i & 1] = W4[base + (i + 2) * 1024 + 3];
            }
            const float bv[8] = {B0.x, B0.y, B0.z, B0.w, B1.x, B1.y, B1.z, B1.w};
            const float cv[8] = {C0.x, C0.y, C0.z, C0.w, C1.x, C1.y, C1.z, C1.w};
            float acc = 0.f;
#pragma unroll
            for (int n = 0; n < 8; ++n) {
                const float a = EXP2(dtp * A2[n]);
                x[n] = fmaf(a, x[n], dtu * bv[n]);
                acc = fmaf(x[n], cv[n], acc);
            }
            acc += __shfl_xor(acc, 32, 64);        // sum the two n-halves
            if (h == 0)
                du_s[lb + i * ISTR2 + c].x = fmaf(uu, Dd, acc);   // y_core
        }
    } else {
        const int k0 = 2 * h;
#pragma unroll 2
        for (int i = 0; i < CL; ++i) {
            const float2 du = du_s[lb + i * ISTR2 + c];
            const float dtp = du.x;
            const float uu = du.y;
            const float dtu = dtp * uu;
            const int l = cg * CL + i;
            float4 B0, B1, C0, C1;
#pragma unroll
            for (int q = 0; q < 4; ++q) {
                (&B0.x)[q] = B_g[(size_t)(b * N + 4 * k0 + q) * L + l];
                (&B1.x)[q] = B_g[(size_t)(b * N + 4 * k0 + 4 + q) * L + l];
                (&C0.x)[q] = C_g[(size_t)(b * N + 4 * k0 + q) * L + l];
                (&C1.x)[q] = C_g[(size_t)(b * N + 4 * k0 + 4 + q) * L + l];
            }
            const float bv[8] = {B0.x, B0.y, B0.z, B0.w, B1.x, B1.y, B1.z, B1.w};
            const float cv[8] = {C0.x, C0.y, C0.z, C0.w, C1.x, C1.y, C1.z, C1.w};
            float acc = 0.f;
#pragma unroll
            for (int n = 0; n < 8; ++n) {
                const float a = EXP2(dtp * A2[n]);
                x[n] = fmaf(a, x[n], dtu * bv[n]);
                acc = fmaf(x[n], cv[n], acc);
            }
            acc += __shfl_xor(acc, 32, 64);
            if (h == 0)
                du_s[lb + i * ISTR2 + c].x = fmaf(uu, Dd, acc);
        }
    }
    // no barrier: epilogue reads wave-private region written by this wave

    // ---- Epilogue: wave-private z read, silu gate, y store ----
    {
        const int l0 = w * 256 + 4 * lane;
        const size_t gb = (size_t)row * L + l0;
        const float4 z4 = *reinterpret_cast<const float4*>(&z_g[gb]);
        const float zv[4] = {z4.x, z4.y, z4.z, z4.w};
        float out[4];
#pragma unroll
        for (int k = 0; k < 4; ++k) {
            const int li = 4 * lane + k;       // local 0..255
            const float yc = du_s[lb + (li & (CL - 1)) * ISTR2 + (li >> 3)].x;
            const float e = EXP2(-zv[k] * LOG2E);
            const float sig = __builtin_amdgcn_rcpf(1.f + e);
            out[k] = yc * (zv[k] * sig);
        }
        *reinterpret_cast<float4*>(&y_g[gb]) = make_float4(out[0], out[1], out[2], out[3]);
    }
}

extern "C" void kernel_launch(void* const* d_in, const int* in_sizes, int n_in,
                              void* d_out, int out_size, void* d_ws, size_t ws_size,
                              hipStream_t stream) {
    const float* u     = (const float*)d_in[0];
    const float* delta = (const float*)d_in[1];
    const float* A     = (const float*)d_in[2];
    const float* B     = (const float*)d_in[3];
    const float* C     = (const float*)d_in[4];
    const float* D     = (const float*)d_in[5];
    const float* z     = (const float*)d_in[6];
    const float* bias  = (const float*)d_in[7];
    const int*   sp    = (const int*)d_in[8];
    float* y = (float*)d_out;

    const size_t w_bytes = (size_t)Bsz * 8192 * sizeof(float4);  // 256 KB
    const bool xf = ws_size >= w_bytes;
    float4* W4 = (float4*)d_ws;

    if (xf) {
        transform_bc_kernel<<<dim3(32, Bsz), 256, 0, stream>>>(B, C, W4);
        mamba_scan15_kernel<true><<<dim3(Bsz * Dm), TPB, 0, stream>>>(
            u, delta, A, B, C, W4, D, z, bias, sp, y);
    } else {
        mamba_scan15_kernel<false><<<dim3(Bsz * Dm), TPB, 0, stream>>>(
            u, delta, A, B, C, W4, D, z, bias, sp, y);
    }
}

// Round 10
// 49.408 us; speedup vs baseline: 2.0348x; 2.0348x over previous
//
#include <hip/hip_runtime.h>
#include <math.h>

// Mamba selective scan:
//   u, delta, z : (2, 2048, 1024) f32 ; A : (2048, 16) f32
//   B, C : (2, 16, 1024) f32 ; D, delta_bias : (2048,) f32 ; softplus flag
// Output y : (2, 2048, 1024) f32
//
// v16 = v12 math (2 waves/row, CL=16, proven combine) + L2-traffic attack:
//   r9 accounting: v12 reads 805 MB of B/C from L2 per launch (96 float4
//   x 524288 threads) -> >=23 us L2-BW floor = the 60 us wall.
//   - RPB 2->4 (512 threads, 8 waves/block, grid 1024)
//   - B/C staged through LDS in TI=2-step tiles (8 KB/tile), reg-staged:
//     pass1 B-tiles double-buffered (1 barrier/tile), pass2 B+C tiles
//     restaged per tile (2 barriers/tile). L2 traffic 805 -> 196 MB.
//   - tile layout XOR-swizzled (k ^= (cg>>1)&3) -> ds_read_b128 <=4-way.
//   - NO register cap (r2/r4). Tripwire: WRITE_SIZE == 16384 KB.
constexpr int Bsz = 2, Dm = 2048, L = 1024, N = 16;
constexpr int CL = 16;          // chunk length (steps per lane)
constexpr int WPR = 2;          // waves per row
constexpr int RPB = 4;          // rows per block
constexpr int TPB = RPB * WPR * 64;  // 512
constexpr int ISTR2 = 65;       // float2 stride per step (64 chunks + 1 pad)
constexpr int LROW2 = CL * ISTR2;    // 1040 float2 per row
constexpr int TI = 2;           // steps per LDS tile
constexpr int NT = CL / TI;     // 8 tiles per pass
constexpr float LOG2E = 1.4426950408889634f;
constexpr float RLOG2E = 0.6931471805599453f;   // ln 2

#define EXP2(x) __builtin_amdgcn_exp2f(x)
// swizzled float4 index within a tile: il in [0,TI), cg in [0,64), k in [0,4)
#define TOFF(il, cg, k) ((il) * 256 + (cg) * 4 + ((k) ^ (((cg) >> 1) & 3)))

// ---------------------------------------------------------------------------
// Transform B,C into scan layout (chunk length 16), k-contiguous:
//   Bs[b*4096 + i*256 + cg*4 + k] = float4 { B[b][4k+q][cg*16+i] } q=0..3
// ---------------------------------------------------------------------------
__global__ __launch_bounds__(256) void transform_bc_kernel(
    const float* __restrict__ B_g, const float* __restrict__ C_g,
    float4* __restrict__ Bs, float4* __restrict__ Cs)
{
    const int o = threadIdx.x + 256 * blockIdx.x;   // 4096 float4 per (b, src)
    const int b = blockIdx.y;
    const float* __restrict__ src = blockIdx.z ? C_g : B_g;
    float4* __restrict__ dst = blockIdx.z ? Cs : Bs;
    const int k = o & 3, cg = (o >> 2) & 63, i = o >> 8;
    const int l = cg * CL + i;
    float4 v;
    v.x = src[(size_t)(b * N + 4 * k + 0) * L + l];
    v.y = src[(size_t)(b * N + 4 * k + 1) * L + l];
    v.z = src[(size_t)(b * N + 4 * k + 2) * L + l];
    v.w = src[(size_t)(b * N + 4 * k + 3) * L + l];
    dst[(size_t)b * 4096 + o] = v;
}

// ---------------------------------------------------------------------------
// Scan kernel. 8 waves/block = 4 rows x 2 waves. Wave handles 32 chunks of
// 16 steps. lane = h*32 + c: h = n-half, c = chunk-in-wave. cg = W*32+c.
// B/C tiles shared by all 4 rows via LDS.
// ---------------------------------------------------------------------------
template<bool XF>
__global__ __launch_bounds__(TPB) void mamba_scan16_kernel(
    const float* __restrict__ u_g, const float* __restrict__ delta_g,
    const float* __restrict__ A_g,
    const float* __restrict__ B_g, const float* __restrict__ C_g,
    const float4* __restrict__ Bs, const float4* __restrict__ Cs,
    const float* __restrict__ D_g, const float* __restrict__ z_g,
    const float* __restrict__ bias_g, const int* __restrict__ sp_g,
    float* __restrict__ y_g)
{
    __shared__ float2 du_s[RPB * LROW2];  // [r][i*65+cg]=(dtp,u); .x later y_core
    __shared__ float4 tb[2][TI * 256];    // two 8KB tile buffers (B / C or dbuf)
    __shared__ float xw_s[RPB][16];       // per-row wave0 totals

    const int tid = threadIdx.x;
    const int wid = tid >> 6;                  // wave id 0..7
    const int lane = tid & 63;
    const int W = wid & 1;                     // wave-in-row
    const int r = wid >> 1;                    // local row 0..3
    const int h = lane >> 5;                   // n-half
    const int c = lane & 31;                   // chunk-in-wave
    const int cg = W * 32 + c;                 // global chunk 0..63
    const int row = blockIdx.x * RPB + r;
    const int b = row >> 11;                   // row / Dm (blocks never straddle)
    const int d = row & (Dm - 1);
    const int sp = sp_g[0];
    const float bias = bias_g[d];
    const int lb = r * LROW2;
    const int t128 = tid & 127;                // thread-in-row (2 waves)
    // staging: thread tid owns float4 #tid of each 512-float4 tile
    const int stg = TOFF(tid >> 8, (tid >> 2) & 63, tid & 3);
    const size_t Bb = (size_t)b * 4096;        // workspace base (float4 units)

    float4 sB, sC;
    if (XF) sB = Bs[Bb + tid];                 // tile 0 of B, issued early

    // ---- Phase 0: coalesced load of delta/u -> step-major packed LDS ----
#pragma unroll
    for (int p = 0; p < 2; ++p) {
        const int l0 = 4 * t128 + 512 * p;
        const size_t gb = (size_t)row * L + l0;
        const float4 d4 = *reinterpret_cast<const float4*>(&delta_g[gb]);
        const float4 u4 = *reinterpret_cast<const float4*>(&u_g[gb]);
        const float dv[4] = {d4.x, d4.y, d4.z, d4.w};
        const float uv[4] = {u4.x, u4.y, u4.z, u4.w};
#pragma unroll
        for (int k = 0; k < 4; ++k) {
            const int li = l0 + k;
            const float t = dv[k] + bias;
            // softplus: max(t,0) + ln(1 + 2^(-|t|*log2e))
            const float e = EXP2(-fabsf(t) * LOG2E);
            const float p_ = sp ? (fmaxf(t, 0.f) +
                                   __builtin_amdgcn_logf(1.f + e) * RLOG2E)
                                : t;
            const int a = (li & (CL - 1)) * ISTR2 + (li >> 4);  // [step][chunk]
            du_s[lb + a] = make_float2(p_, uv[k]);
        }
    }
    if (XF) tb[0][stg] = sB;                   // stage tile 0 (B) for pass 1
    __syncthreads();

    float A2[8];
#pragma unroll
    for (int g = 0; g < 2; ++g) {
        const float4 a4 = *reinterpret_cast<const float4*>(&A_g[d * N + h * 8 + g * 4]);
        A2[g * 4 + 0] = a4.x * LOG2E; A2[g * 4 + 1] = a4.y * LOG2E;
        A2[g * 4 + 2] = a4.z * LOG2E; A2[g * 4 + 3] = a4.w * LOG2E;
    }
    const int k0 = 2 * h;                      // my first n-quad
    const float Dd = D_g[d];

    // ---- Pass 1: chunk-local zero-init scan; B via LDS tiles (dbuf) ----
    float x[8];
#pragma unroll
    for (int n = 0; n < 8; ++n) x[n] = 0.f;
    float ssum = 0.f;

    if (XF) {
#pragma unroll 1
        for (int t = 0; t < NT; ++t) {
            if (t + 1 < NT) sB = Bs[Bb + (t + 1) * 512 + tid];  // prefetch
#pragma unroll
            for (int il = 0; il < TI; ++il) {
                const int i = t * TI + il;
                const float2 du = du_s[lb + i * ISTR2 + cg];
                const float dtp = du.x;
                const float dtu = du.x * du.y;
                ssum += dtp;
                const float4 B0 = tb[t & 1][TOFF(il, cg, k0)];
                const float4 B1 = tb[t & 1][TOFF(il, cg, k0 + 1)];
                const float bv[8] = {B0.x, B0.y, B0.z, B0.w, B1.x, B1.y, B1.z, B1.w};
#pragma unroll
                for (int n = 0; n < 8; ++n) {
                    const float a = EXP2(dtp * A2[n]);
                    x[n] = fmaf(a, x[n], dtu * bv[n]);
                }
            }
            if (t + 1 < NT) tb[(t + 1) & 1][stg] = sB;  // write other buffer
            __syncthreads();                            // end tile epoch
        }
    } else {
#pragma unroll 4
        for (int i = 0; i < CL; ++i) {
            const float2 du = du_s[lb + i * ISTR2 + cg];
            const float dtp = du.x;
            const float dtu = du.x * du.y;
            ssum += dtp;
            const int l = cg * CL + i;
            float4 B0, B1;
#pragma unroll
            for (int q = 0; q < 4; ++q) {
                (&B0.x)[q] = B_g[(size_t)(b * N + 4 * k0 + q) * L + l];
                (&B1.x)[q] = B_g[(size_t)(b * N + 4 * k0 + 4 + q) * L + l];
            }
            const float bv[8] = {B0.x, B0.y, B0.z, B0.w, B1.x, B1.y, B1.z, B1.w};
#pragma unroll
            for (int n = 0; n < 8; ++n) {
                const float a = EXP2(dtp * A2[n]);
                x[n] = fmaf(a, x[n], dtu * bv[n]);
            }
        }
    }

    // issue pass-2 tile 0 loads early (latency hides under combine)
    if (XF) { sB = Bs[Bb + tid]; sC = Cs[Bb + tid]; }

    // ---- Combine level 1: 32-lane segmented inclusive scan of (P, x) ----
    float P[8];
#pragma unroll
    for (int n = 0; n < 8; ++n) P[n] = EXP2(A2[n] * ssum);
#pragma unroll
    for (int s = 1; s < 32; s <<= 1) {
        const bool ok = (c >= s);
#pragma unroll
        for (int n = 0; n < 8; ++n) {
            const float xp = __shfl_up(x[n], s, 32);
            const float Pp = __shfl_up(P[n], s, 32);
            if (ok) {
                x[n] = fmaf(P[n], xp, x[n]);
                P[n] = P[n] * Pp;
            }
        }
    }

    // ---- Combine level 2 publish + stage pass-2 tile 0; ONE barrier ----
    if (W == 0 && c == 31) {
#pragma unroll
        for (int n = 0; n < 8; ++n) xw_s[r][h * 8 + n] = x[n];
    }
    if (XF) { tb[0][stg] = sB; tb[1][stg] = sC; }   // pass1 reads all done
    __syncthreads();

    // exclusive shift within segment + wave1 prepends wave0's total
    float xt[8];
#pragma unroll
    for (int n = 0; n < 8; ++n) xt[n] = xw_s[r][h * 8 + n];
#pragma unroll
    for (int n = 0; n < 8; ++n) {
        const float xi = __shfl_up(x[n], 1, 32);
        const float Pi = __shfl_up(P[n], 1, 32);
        const float xe = (c == 0) ? 0.f : xi;
        const float Pe = (c == 0) ? 1.f : Pi;
        x[n] = W ? fmaf(Pe, xt[n], xe) : xe;
    }

    // ---- Pass 2: rescan with init states; B+C via LDS tiles ----
    if (XF) {
#pragma unroll 1
        for (int t = 0; t < NT; ++t) {
            if (t + 1 < NT) {
                sB = Bs[Bb + (t + 1) * 512 + tid];   // prefetch next tile
                sC = Cs[Bb + (t + 1) * 512 + tid];
            }
#pragma unroll
            for (int il = 0; il < TI; ++il) {
                const int i = t * TI + il;
                const float2 du = du_s[lb + i * ISTR2 + cg];
                const float dtp = du.x;
                const float uu = du.y;
                const float dtu = dtp * uu;
                const float4 B0 = tb[0][TOFF(il, cg, k0)];
                const float4 B1 = tb[0][TOFF(il, cg, k0 + 1)];
                const float4 C0 = tb[1][TOFF(il, cg, k0)];
                const float4 C1 = tb[1][TOFF(il, cg, k0 + 1)];
                const float bv[8] = {B0.x, B0.y, B0.z, B0.w, B1.x, B1.y, B1.z, B1.w};
                const float cv[8] = {C0.x, C0.y, C0.z, C0.w, C1.x, C1.y, C1.z, C1.w};
                float acc = 0.f;
#pragma unroll
                for (int n = 0; n < 8; ++n) {
                    const float a = EXP2(dtp * A2[n]);
                    x[n] = fmaf(a, x[n], dtu * bv[n]);
                    acc = fmaf(x[n], cv[n], acc);
                }
                acc += __shfl_xor(acc, 32, 64);    // sum the two n-halves
                if (h == 0)
                    du_s[lb + i * ISTR2 + cg].x = fmaf(uu, Dd, acc);   // y_core
            }
            __syncthreads();                       // all waves done with tile t
            if (t + 1 < NT) {
                tb[0][stg] = sB;                   // restage same buffers
                tb[1][stg] = sC;
                __syncthreads();                   // tile t+1 visible
            }
        }
    } else {
#pragma unroll 4
        for (int i = 0; i < CL; ++i) {
            const float2 du = du_s[lb + i * ISTR2 + cg];
            const float dtp = du.x;
            const float uu = du.y;
            const float dtu = dtp * uu;
            const int l = cg * CL + i;
            float4 B0, B1, C0, C1;
#pragma unroll
            for (int q = 0; q < 4; ++q) {
                (&B0.x)[q] = B_g[(size_t)(b * N + 4 * k0 + q) * L + l];
                (&B1.x)[q] = B_g[(size_t)(b * N + 4 * k0 + 4 + q) * L + l];
                (&C0.x)[q] = C_g[(size_t)(b * N + 4 * k0 + q) * L + l];
                (&C1.x)[q] = C_g[(size_t)(b * N + 4 * k0 + 4 + q) * L + l];
            }
            const float bv[8] = {B0.x, B0.y, B0.z, B0.w, B1.x, B1.y, B1.z, B1.w};
            const float cv[8] = {C0.x, C0.y, C0.z, C0.w, C1.x, C1.y, C1.z, C1.w};
            float acc = 0.f;
#pragma unroll
            for (int n = 0; n < 8; ++n) {
                const float a = EXP2(dtp * A2[n]);
                x[n] = fmaf(a, x[n], dtu * bv[n]);
                acc = fmaf(x[n], cv[n], acc);
            }
            acc += __shfl_xor(acc, 32, 64);
            if (h == 0)
                du_s[lb + i * ISTR2 + cg].x = fmaf(uu, Dd, acc);
        }
        __syncthreads();
    }

    // ---- Epilogue: coalesced z read, silu gate, coalesced y store ----
    // (last loop iteration ended with an unconditional __syncthreads)
#pragma unroll
    for (int p = 0; p < 2; ++p) {
        const int l0 = 4 * t128 + 512 * p;
        const size_t gb = (size_t)row * L + l0;
        const float4 z4 = *reinterpret_cast<const float4*>(&z_g[gb]);
        const float zv[4] = {z4.x, z4.y, z4.z, z4.w};
        float out[4];
#pragma unroll
        for (int k = 0; k < 4; ++k) {
            const int li = l0 + k;
            const float yc = du_s[lb + (li & (CL - 1)) * ISTR2 + (li >> 4)].x;
            const float e = EXP2(-zv[k] * LOG2E);
            const float sig = __builtin_amdgcn_rcpf(1.f + e);
            out[k] = yc * (zv[k] * sig);
        }
        *reinterpret_cast<float4*>(&y_g[gb]) = make_float4(out[0], out[1], out[2], out[3]);
    }
}

extern "C" void kernel_launch(void* const* d_in, const int* in_sizes, int n_in,
                              void* d_out, int out_size, void* d_ws, size_t ws_size,
                              hipStream_t stream) {
    const float* u     = (const float*)d_in[0];
    const float* delta = (const float*)d_in[1];
    const float* A     = (const float*)d_in[2];
    const float* B     = (const float*)d_in[3];
    const float* C     = (const float*)d_in[4];
    const float* D     = (const float*)d_in[5];
    const float* z     = (const float*)d_in[6];
    const float* bias  = (const float*)d_in[7];
    const int*   sp    = (const int*)d_in[8];
    float* y = (float*)d_out;

    const size_t bc_bytes = (size_t)Bsz * 4096 * sizeof(float4);  // 128 KB each
    const bool xf = ws_size >= 2 * bc_bytes;
    float4* Bs = (float4*)d_ws;
    float4* Cs = (float4*)((char*)d_ws + bc_bytes);

    if (xf) {
        transform_bc_kernel<<<dim3(16, Bsz, 2), 256, 0, stream>>>(B, C, Bs, Cs);
        mamba_scan16_kernel<true><<<dim3((Bsz * Dm) / RPB), TPB, 0, stream>>>(
            u, delta, A, B, C, Bs, Cs, D, z, bias, sp, y);
    } else {
        mamba_scan16_kernel<false><<<dim3((Bsz * Dm) / RPB), TPB, 0, stream>>>(
            u, delta, A, B, C, Bs, Cs, D, z, bias, sp, y);
    }
}